// Round 1
// baseline (983.618 us; speedup 1.0000x reference)
//
#include <hip/hip_runtime.h>

#define TILE 64
#define HALO 10
#define PADW 84   // TILE + 2*HALO
#define KS   21
#define HDIM 768

__device__ __forceinline__ int reflect_idx(int x, int n) {
    // single reflection is sufficient since pad (10) < n (768)
    if (x < 0) x = -x;
    if (x >= n) x = 2 * n - 2 - x;
    return x;
}

__global__ __launch_bounds__(256)
void blur_by_kernel(const float* __restrict__ in,
                    const float* __restrict__ kern,
                    float* __restrict__ out) {
    __shared__ float tile[PADW * PADW];

    const int bx = blockIdx.x;          // tile col
    const int by = blockIdx.y;          // tile row
    const int bc = blockIdx.z;          // b*3 + c
    const int b  = bc / 3;
    const int tid = threadIdx.x;

    const float* plane = in + (size_t)bc * (HDIM * HDIM);

    const int y0 = by * TILE - HALO;
    const int x0 = bx * TILE - HALO;

    // ---- stage 84x84 input tile into LDS with reflect padding ----
    for (int idx = tid; idx < PADW * PADW; idx += 256) {
        int r = idx / PADW;
        int c = idx - r * PADW;
        int gy = reflect_idx(y0 + r, HDIM);
        int gx = reflect_idx(x0 + c, HDIM);
        tile[idx] = plane[gy * HDIM + gx];
    }
    __syncthreads();

    const float* kb = kern + b * (KS * KS);   // block-uniform -> scalar loads

    const int tx = tid & 15;
    const int ty = tid >> 4;
    const int ox = tx * 4;   // within-tile output col base
    const int oy = ty * 4;   // within-tile output row base

    float acc[4][4] = {};

    for (int ki = 0; ki < KS; ++ki) {
        float kv[KS];
        #pragma unroll
        for (int kj = 0; kj < KS; ++kj) kv[kj] = kb[ki * KS + kj];

        #pragma unroll
        for (int r = 0; r < 4; ++r) {
            const float* lrow = &tile[(oy + r + ki) * PADW + ox];
            float x[24];
            #pragma unroll
            for (int j = 0; j < 6; ++j) {
                float4 v = *(const float4*)(lrow + 4 * j);
                x[4*j + 0] = v.x; x[4*j + 1] = v.y;
                x[4*j + 2] = v.z; x[4*j + 3] = v.w;
            }
            #pragma unroll
            for (int kj = 0; kj < KS; ++kj) {
                #pragma unroll
                for (int c = 0; c < 4; ++c)
                    acc[r][c] = fmaf(kv[kj], x[kj + c], acc[r][c]);
            }
        }
    }

    float* oplane = out + (size_t)bc * (HDIM * HDIM);
    const int gx0 = bx * TILE + ox;
    const int gy0 = by * TILE + oy;
    #pragma unroll
    for (int r = 0; r < 4; ++r) {
        float4 v = make_float4(acc[r][0], acc[r][1], acc[r][2], acc[r][3]);
        *(float4*)&oplane[(gy0 + r) * HDIM + gx0] = v;
    }
}

extern "C" void kernel_launch(void* const* d_in, const int* in_sizes, int n_in,
                              void* d_out, int out_size, void* d_ws, size_t ws_size,
                              hipStream_t stream) {
    const float* in   = (const float*)d_in[0];   // (16,3,768,768) fp32
    const float* kern = (const float*)d_in[1];   // (16,21,21) fp32
    float* out = (float*)d_out;

    dim3 grid(HDIM / TILE, HDIM / TILE, 16 * 3); // 12 x 12 x 48
    dim3 block(256);
    blur_by_kernel<<<grid, block, 0, stream>>>(in, kern, out);
}

// Round 2
// 459.424 us; speedup vs baseline: 2.1410x; 2.1410x over previous
//
#include <hip/hip_runtime.h>

#define KS   21
#define HALO 10
#define TH   16
#define TW   256
#define PH   (TH + 2*HALO)   // 36
#define PW   (TW + 2*HALO)   // 276 floats = 69 quads, 16B-aligned rows
#define HDIM 768

__device__ __forceinline__ int reflect_idx(int x, int n) {
    if (x < 0) x = -x;
    if (x >= n) x = 2 * n - 2 - x;
    return x;
}

__global__ __launch_bounds__(256, 4)
void blur_by_kernel(const float* __restrict__ in,
                    const float* __restrict__ kern,
                    float* __restrict__ out) {
    __shared__ float tile[PH * PW];   // 9936 floats = 38.8 KB -> 4 blocks/CU

    const int bx  = blockIdx.x;   // 0..2   col tile (256 wide)
    const int by  = blockIdx.y;   // 0..47  row tile (16 tall)
    const int bc  = blockIdx.z;   // 0..47  b*3+c
    const int b   = bc / 3;
    const int tid = threadIdx.x;
    const int lane = tid & 63;
    const int w    = tid >> 6;    // wave id 0..3 -> output rows 4w..4w+3

    const float* plane = in + (size_t)bc * (HDIM * HDIM);
    const int y0 = by * TH - HALO;
    const int x0 = bx * TW - HALO;

    // ---- stage 36x276 input tile with reflect padding (coalesced, 2-way LDS writes) ----
    for (int idx = tid; idx < PH * PW; idx += 256) {
        int r = idx / PW;
        int c = idx - r * PW;
        tile[idx] = plane[reflect_idx(y0 + r, HDIM) * HDIM + reflect_idx(x0 + c, HDIM)];
    }
    __syncthreads();

    const float* kb = kern + b * (KS * KS);  // block-uniform -> scalar loads

    float acc[4][4] = {};
    const int colbase = lane * 4;            // lane's output cols (tile-rel)

    // Wave w consumes padded rows 4w .. 4w+23; all 64 lanes read the SAME row
    // each iteration (wave-uniform base + 16B/lane monotone offsets -> conflict-free).
    for (int t = 0; t < TH / 2 + KS - 1 + 0; ++t) {  // t = 0..23
        if (t >= 24) break;
        const float* lrow = &tile[(w * 4 + t) * PW + colbase];
        float x[24];
        #pragma unroll
        for (int j = 0; j < 6; ++j) {
            float4 v = *(const float4*)(lrow + 4 * j);
            x[4*j + 0] = v.x; x[4*j + 1] = v.y;
            x[4*j + 2] = v.z; x[4*j + 3] = v.w;
        }
        // out row r uses input row (4w + r + ki): valid when ki = t - r in [0,20]
        #pragma unroll
        for (int r = 0; r < 4; ++r) {
            int ki = t - r;
            if (ki >= 0 && ki < KS) {         // wave-uniform predicate, r compile-time
                const float* krow = kb + ki * KS;
                #pragma unroll
                for (int kj = 0; kj < KS; ++kj) {
                    float kv = krow[kj];
                    #pragma unroll
                    for (int c = 0; c < 4; ++c)
                        acc[r][c] = fmaf(kv, x[kj + c], acc[r][c]);
                }
            }
        }
    }

    float* oplane = out + (size_t)bc * (HDIM * HDIM);
    const int gx = bx * TW + colbase;
    const int gy = by * TH + w * 4;
    #pragma unroll
    for (int r = 0; r < 4; ++r) {
        float4 v = make_float4(acc[r][0], acc[r][1], acc[r][2], acc[r][3]);
        *(float4*)&oplane[(size_t)(gy + r) * HDIM + gx] = v;
    }
}

extern "C" void kernel_launch(void* const* d_in, const int* in_sizes, int n_in,
                              void* d_out, int out_size, void* d_ws, size_t ws_size,
                              hipStream_t stream) {
    const float* in   = (const float*)d_in[0];   // (16,3,768,768) fp32
    const float* kern = (const float*)d_in[1];   // (16,21,21) fp32
    float* out = (float*)d_out;

    dim3 grid(HDIM / TW, HDIM / TH, 16 * 3);     // 3 x 48 x 48
    dim3 block(256);
    blur_by_kernel<<<grid, block, 0, stream>>>(in, kern, out);
}

// Round 3
// 426.299 us; speedup vs baseline: 2.3073x; 1.0777x over previous
//
#include <hip/hip_runtime.h>

#define KS   21
#define HALO 10
#define TH   16
#define TW   256
#define PH   (TH + 2*HALO)   // 36
#define PW   (TW + 2*HALO)   // 276 floats, rows 16B-aligned
#define HDIM 768

__device__ __forceinline__ int reflect_idx(int x, int n) {
    if (x < 0) x = -x;
    if (x >= n) x = 2 * n - 2 - x;
    return x;
}

__global__ __launch_bounds__(256, 3)   // VGPR cap ~170; occupancy is LDS-capped (4 blk/CU) anyway
void blur_by_kernel(const float* __restrict__ in,
                    const float* __restrict__ kern,
                    float* __restrict__ out) {
    __shared__ float tile[PH * PW];   // 39.7 KB -> 4 blocks/CU

    const int bx  = blockIdx.x;   // 0..2   col tile
    const int by  = blockIdx.y;   // 0..47  row tile
    const int bc  = blockIdx.z;   // b*3+c
    const int b   = bc / 3;
    const int tid = threadIdx.x;
    const int lane = tid & 63;
    const int w    = tid >> 6;    // wave id -> output rows 4w..4w+3

    const float* plane = in + (size_t)bc * (HDIM * HDIM);
    const int y0 = by * TH - HALO;
    const int x0 = bx * TW - HALO;

    for (int idx = tid; idx < PH * PW; idx += 256) {
        int r = idx / PW;
        int c = idx - r * PW;
        tile[idx] = plane[reflect_idx(y0 + r, HDIM) * HDIM + reflect_idx(x0 + c, HDIM)];
    }
    __syncthreads();

    const float* kb = kern + b * (KS * KS);  // block-uniform -> scalar loads

    float acc[4][4] = {};
    float4 x4[6];
    const float* xs = (const float*)x4;
    const int colbase = lane * 4;

    // all 64 lanes read the SAME padded row: wave-uniform base + contiguous
    // 16B/lane -> conflict-free ds_read_b128 (m97 pattern)
    #define LOADROW(t)                                                        \
        {                                                                     \
            const float4* lrow = (const float4*)&tile[(w * 4 + (t)) * PW + colbase]; \
            _Pragma("unroll")                                                 \
            for (int j = 0; j < 6; ++j) x4[j] = lrow[j];                      \
        }

    #define FMAROW(r, ki)                                                     \
        {                                                                     \
            const float* krow = kb + (ki) * KS;                               \
            _Pragma("unroll")                                                 \
            for (int kj = 0; kj < KS; ++kj) {                                 \
                float kv = krow[kj];                                          \
                _Pragma("unroll")                                             \
                for (int c = 0; c < 4; ++c)                                   \
                    acc[r][c] = fmaf(kv, xs[kj + c], acc[r][c]);              \
            }                                                                 \
        }

    // ---- ramp: t = 0..2 (partial r validity, compile-time resolved) ----
    #pragma unroll
    for (int t = 0; t < 3; ++t) {
        LOADROW(t);
        #pragma unroll
        for (int r = 0; r < 4; ++r)
            if (t - r >= 0) FMAROW(r, t - r);
    }

    // ---- steady: t = 3..20, branch-free, all 4 rows valid ----
    for (int t = 3; t <= 20; ++t) {
        LOADROW(t);
        #pragma unroll
        for (int r = 0; r < 4; ++r)
            FMAROW(r, t - r);
    }

    // ---- drain: t = 21..23 ----
    #pragma unroll
    for (int t = 21; t < 24; ++t) {
        LOADROW(t);
        #pragma unroll
        for (int r = 0; r < 4; ++r)
            if (t - r <= 20) FMAROW(r, t - r);
    }

    float* oplane = out + (size_t)bc * (HDIM * HDIM);
    const int gx = bx * TW + colbase;
    const int gy = by * TH + w * 4;
    #pragma unroll
    for (int r = 0; r < 4; ++r) {
        float4 v = make_float4(acc[r][0], acc[r][1], acc[r][2], acc[r][3]);
        *(float4*)&oplane[(size_t)(gy + r) * HDIM + gx] = v;
    }
}

extern "C" void kernel_launch(void* const* d_in, const int* in_sizes, int n_in,
                              void* d_out, int out_size, void* d_ws, size_t ws_size,
                              hipStream_t stream) {
    const float* in   = (const float*)d_in[0];   // (16,3,768,768) fp32
    const float* kern = (const float*)d_in[1];   // (16,21,21) fp32
    float* out = (float*)d_out;

    dim3 grid(HDIM / TW, HDIM / TH, 16 * 3);     // 3 x 48 x 48
    dim3 block(256);
    blur_by_kernel<<<grid, block, 0, stream>>>(in, kern, out);
}